// Round 6
// baseline (280.230 us; speedup 1.0000x reference)
//
#include <hip/hip_runtime.h>
#include <stdint.h>

// Problem constants
#define Bsz 4096
#define Tn  64      // scan length (char_seq[:, :-1])
#define T1n 65
#define Hn  64
#define Pn  50
#define Vn  32

typedef __attribute__((ext_vector_type(8))) short short8;
typedef __attribute__((ext_vector_type(4))) float floatx4;

__device__ __forceinline__ float bf2f(unsigned short u) {
  union { unsigned int i; float f; } x; x.i = ((unsigned int)u) << 16; return x.f;
}
__device__ __forceinline__ unsigned short f2bf(float f) {
  union { float f; unsigned int i; } x; x.f = f;
  return (unsigned short)((x.i + 0x7FFFu + ((x.i >> 16) & 1u)) >> 16);
}
__device__ __forceinline__ float fast_sigmoid(float x) {
  return __builtin_amdgcn_rcpf(1.f + __expf(-x));   // v_rcp, not IEEE div
}
__device__ __forceinline__ float fast_tanh(float x) {
  return 1.f - 2.f * __builtin_amdgcn_rcpf(1.f + __expf(2.f * x));
}

// B-operand fragment for mfma_f32_16x16x32_bf16 from row-major (K x ncols) fp32 weights.
__device__ __forceinline__ short8 load_bfrag(const float* __restrict__ W, int ncols, int col, int kbase) {
  short8 f;
#pragma unroll
  for (int j = 0; j < 8; ++j) f[j] = (short)f2bf(W[(long)(kbase + j) * ncols + col]);
  return f;
}

__global__ void zero_kernel(float* __restrict__ ws) {
  if (threadIdx.x < 2) ws[threadIdx.x] = 0.f;
}

// ---------------- Kernel 1: GRU scan only. 256 blocks x 256 threads (4 waves).
// Block owns 16 batch rows; wave w owns hidden cols [16w,16w+16) in MFMA
// C-layout. h history in LDS per 16-step chunk, bulk-dumped to global (d_out
// region, bf16 [b][t][64]) once per chunk. No softmax, no shuffles, no
// per-step global traffic.
__launch_bounds__(256)
__global__ void gru_scan(const float* __restrict__ phon,
                         const int* __restrict__ cs,
                         const float* __restrict__ emb,
                         const float* __restrict__ Wrx, const float* __restrict__ brx,
                         const float* __restrict__ Wrh, const float* __restrict__ brh,
                         const float* __restrict__ Wzx, const float* __restrict__ bzx,
                         const float* __restrict__ Wzh, const float* __restrict__ bzh,
                         const float* __restrict__ Whx, const float* __restrict__ bhx,
                         const float* __restrict__ Whh, const float* __restrict__ bhh,
                         unsigned short* __restrict__ histg) {
  __shared__ unsigned short tbl_s[3 * 32 * 66];              // bf16 [g][v][66]
  __shared__ __align__(16) unsigned short hist_s[16 * 1152]; // bf16 h[slot][m][72]
  __shared__ __align__(16) unsigned short rh_s[16 * 72];     // bf16 r*h
  __shared__ unsigned int code4_s[64 * 4];                   // packed codes [t][q]
  __shared__ unsigned short emb_s[32 * 64];
  __shared__ unsigned short ph_s[16 * 52];
  __shared__ int det_s[1];

  const int tid = threadIdx.x;
  const int b0 = blockIdx.x * 16;
  const int w = tid >> 6, lane = tid & 63, q = lane >> 4, c16 = lane & 15;
  const int jcol = w * 16 + c16;

  // int32-vs-int64 detection (int64 codes 0..31 have zero odd words)
  if (tid == 0) det_s[0] = 0;
  __syncthreads();
  if (tid < 128 && cs[2 * tid + 1] != 0) atomicOr(&det_s[0], 1);
  __syncthreads();
  const bool is64 = (det_s[0] == 0);

  // staging
  for (int i = tid; i < 16 * 72; i += 256) hist_s[15 * 1152 + i] = 0;  // h0
  for (int i = tid; i < 32 * 64; i += 256) emb_s[i] = f2bf(emb[i]);
  for (int i = tid; i < 16 * Pn; i += 256) {
    int m = i / Pn, p = i - m * Pn;
    ph_s[m * 52 + p] = f2bf(phon[(long)(b0 + m) * Pn + p]);
  }
  {  // packed codes: one u32 per (t, q) = codes of rows q*4..q*4+3 at step t
    int t = tid >> 2, qq = tid & 3;
    unsigned int pk = 0;
#pragma unroll
    for (int r = 0; r < 4; ++r) {
      long idx = (long)(b0 + qq * 4 + r) * T1n + t;
      int c = is64 ? cs[2 * idx] : cs[idx];
      pk |= ((unsigned int)(c & 255)) << (8 * r);
    }
    code4_s[t * 4 + qq] = pk;
  }

  // recurrent weight B-fragments (t-invariant)
  short8 Brh0 = load_bfrag(Wrh, Hn, jcol, q * 8);
  short8 Brh1 = load_bfrag(Wrh, Hn, jcol, 32 + q * 8);
  short8 Bzh0 = load_bfrag(Wzh, Hn, jcol, q * 8);
  short8 Bzh1 = load_bfrag(Wzh, Hn, jcol, 32 + q * 8);
  short8 Bhh0 = load_bfrag(Whh, Hn, jcol, q * 8);
  short8 Bhh1 = load_bfrag(Whh, Hn, jcol, 32 + q * 8);

  __syncthreads();

  // TBL: tbl_s[g][v][j] = bf16( emb[v] @ W_gx[:64] + b_gx[j] + b_gh[j] )
  for (int g = 0; g < 3; ++g) {
    const float* W  = (g == 0) ? Wrx : (g == 1) ? Wzx : Whx;
    const float* bx = (g == 0) ? brx : (g == 1) ? bzx : bhx;
    const float* bh = (g == 0) ? brh : (g == 1) ? bzh : bhh;
    float acc[8] = {0.f, 0.f, 0.f, 0.f, 0.f, 0.f, 0.f, 0.f};
    float bias = bx[lane] + bh[lane];
    for (int d = 0; d < Hn; ++d) {
      float wv = W[(long)d * Hn + lane];
#pragma unroll
      for (int k = 0; k < 8; ++k)
        acc[k] += bf2f(emb_s[(w + 4 * k) * Hn + d]) * wv;
    }
#pragma unroll
    for (int k = 0; k < 8; ++k)
      tbl_s[g * 2112 + (w + 4 * k) * 66 + lane] = f2bf(acc[k] + bias);
  }

  // PH: per-lane registers, rows q*4+r, col jcol
  float ph_r[4] = {0.f, 0.f, 0.f, 0.f};
  float ph_z[4] = {0.f, 0.f, 0.f, 0.f};
  float ph_h[4] = {0.f, 0.f, 0.f, 0.f};
  for (int p = 0; p < Pn; ++p) {
    float wr = Wrx[(long)(Hn + p) * Hn + jcol];
    float wz = Wzx[(long)(Hn + p) * Hn + jcol];
    float wh = Whx[(long)(Hn + p) * Hn + jcol];
#pragma unroll
    for (int r = 0; r < 4; ++r) {
      float xv = bf2f(ph_s[(q * 4 + r) * 52 + p]);
      ph_r[r] += xv * wr; ph_z[r] += xv * wz; ph_h[r] += xv * wh;
    }
  }

  float h[4] = {0.f, 0.f, 0.f, 0.f};

  __syncthreads();   // tbl_s / code4_s ready; hist_s[15] zeroed

  for (int qi = 0; qi < 4; ++qi) {
    for (int tt = 0; tt < 16; ++tt) {
      const int t = qi * 16 + tt;
      unsigned int pk = code4_s[t * 4 + q];

      // phase 1: r,z = sigmoid(TBL[code] + PH + h @ W)
      const unsigned short* hp = &hist_s[((tt + 15) & 15) * 1152];
      short8 a0 = *(const short8*)&hp[c16 * 72 + q * 8];
      short8 a1 = *(const short8*)&hp[c16 * 72 + 32 + q * 8];
      floatx4 accr = {0.f, 0.f, 0.f, 0.f}, accz = {0.f, 0.f, 0.f, 0.f};
      accr = __builtin_amdgcn_mfma_f32_16x16x32_bf16(a0, Brh0, accr, 0, 0, 0);
      accr = __builtin_amdgcn_mfma_f32_16x16x32_bf16(a1, Brh1, accr, 0, 0, 0);
      accz = __builtin_amdgcn_mfma_f32_16x16x32_bf16(a0, Bzh0, accz, 0, 0, 0);
      accz = __builtin_amdgcn_mfma_f32_16x16x32_bf16(a1, Bzh1, accz, 0, 0, 0);
      float z[4];
#pragma unroll
      for (int r = 0; r < 4; ++r) {
        int cr = (pk >> (8 * r)) & 255;
        float xr = bf2f(tbl_s[0 * 2112 + cr * 66 + jcol]) + ph_r[r] + accr[r];
        float rr = fast_sigmoid(xr);
        float xz = bf2f(tbl_s[1 * 2112 + cr * 66 + jcol]) + ph_z[r] + accz[r];
        z[r] = fast_sigmoid(xz);
        rh_s[(q * 4 + r) * 72 + jcol] = f2bf(rr * h[r]);
      }
      __syncthreads();  // A (lgkm only)

      // phase 2: c = tanh(TBL + PH + (r*h) @ W_hh); h = (1-z)h + z c
      short8 p0 = *(const short8*)&rh_s[c16 * 72 + q * 8];
      short8 p1 = *(const short8*)&rh_s[c16 * 72 + 32 + q * 8];
      floatx4 accc = {0.f, 0.f, 0.f, 0.f};
      accc = __builtin_amdgcn_mfma_f32_16x16x32_bf16(p0, Bhh0, accc, 0, 0, 0);
      accc = __builtin_amdgcn_mfma_f32_16x16x32_bf16(p1, Bhh1, accc, 0, 0, 0);
      unsigned short* hw = &hist_s[tt * 1152];
#pragma unroll
      for (int r = 0; r < 4; ++r) {
        int cr = (pk >> (8 * r)) & 255;
        float xh = bf2f(tbl_s[2 * 2112 + cr * 66 + jcol]) + ph_h[r] + accc[r];
        float c = fast_tanh(xh);
        float hn = (1.f - z[r]) * h[r] + z[r] * c;
        h[r] = hn;
        hw[(q * 4 + r) * 72 + jcol] = f2bf(hn);
      }
      __syncthreads();  // B (lgkm only)
    }

    // bulk dump of this chunk's h history to global (coalesced 16B units)
    for (int u = tid; u < 2048; u += 256) {
      int slot = u >> 7, rem = u & 127;
      int m = rem >> 3, grp = rem & 7;
      short8 v = *(const short8*)&hist_s[slot * 1152 + m * 72 + grp * 8];
      *(short8*)&histg[(((long)(b0 + m)) * Tn + qi * 16 + slot) * Hn + grp * 8] = v;
    }
    // no barrier needed: next chunk's first hist_s write is 2 barriers away
  }
}

// ---------------- Kernel 2: projection + log-softmax + masked NLL.
// 4096 blocks (one batch row each) x 256 threads (4 waves); wave w handles
// t in [16w, 16w+16) as 16 MFMA rows. Reads bf16 h cells, overwrites the
// same 128B cells with fp32 logits (read-before-write within the wave).
__launch_bounds__(256)
__global__ void proj_kernel(const int* __restrict__ cs,
                            const float* __restrict__ Wpj, const float* __restrict__ bpj_g,
                            float* __restrict__ ws,
                            float* __restrict__ outp) {
  __shared__ unsigned char targ_s[64];
  __shared__ int det_s[1];
  __shared__ float red_s[8];

  const int tid = threadIdx.x;
  const long b = blockIdx.x;
  const int w = tid >> 6, lane = tid & 63, q = lane >> 4, c16 = lane & 15;
  const unsigned short* hist = (const unsigned short*)outp;

  if (tid == 0) det_s[0] = 0;
  __syncthreads();
  if (tid < 128 && cs[2 * tid + 1] != 0) atomicOr(&det_s[0], 1);
  __syncthreads();
  const bool is64 = (det_s[0] == 0);
  if (tid < 64) {
    long idx = b * T1n + tid + 1;
    targ_s[tid] = (unsigned char)(is64 ? cs[2 * idx] : cs[idx]);
  }

  short8 Bp00 = load_bfrag(Wpj, Vn, c16,      q * 8);
  short8 Bp01 = load_bfrag(Wpj, Vn, c16,      32 + q * 8);
  short8 Bp10 = load_bfrag(Wpj, Vn, 16 + c16, q * 8);
  short8 Bp11 = load_bfrag(Wpj, Vn, 16 + c16, 32 + q * 8);
  const float bpj0 = bpj_g[c16], bpj1 = bpj_g[16 + c16];
  __syncthreads();

  // A-frags: 16 cells (t = w*16 + m), lane row m = c16
  const long cell0 = b * Tn + w * 16;
  const short8 ha0 = *(const short8*)&hist[(cell0 + c16) * Hn + q * 8];
  const short8 ha1 = *(const short8*)&hist[(cell0 + c16) * Hn + 32 + q * 8];
  floatx4 l0 = {0.f, 0.f, 0.f, 0.f}, l1 = {0.f, 0.f, 0.f, 0.f};
  l0 = __builtin_amdgcn_mfma_f32_16x16x32_bf16(ha0, Bp00, l0, 0, 0, 0);
  l0 = __builtin_amdgcn_mfma_f32_16x16x32_bf16(ha1, Bp01, l0, 0, 0, 0);
  l1 = __builtin_amdgcn_mfma_f32_16x16x32_bf16(ha0, Bp10, l1, 0, 0, 0);
  l1 = __builtin_amdgcn_mfma_f32_16x16x32_bf16(ha1, Bp11, l1, 0, 0, 0);

  float nll_acc = 0.f, cnt_acc = 0.f;
#pragma unroll
  for (int r = 0; r < 4; ++r) {
    int m = q * 4 + r;                    // cell row
    int t = w * 16 + m;
    float lg0 = l0[r] + bpj0, lg1 = l1[r] + bpj1;
    float mx = fmaxf(lg0, lg1);
#pragma unroll
    for (int off = 8; off >= 1; off >>= 1) mx = fmaxf(mx, __shfl_xor(mx, off));
    float s = __expf(lg0 - mx) + __expf(lg1 - mx);
#pragma unroll
    for (int off = 8; off >= 1; off >>= 1) s += __shfl_xor(s, off);
    float lse = mx + __logf(s);
    long base = (b * Tn + t) * Vn;
    outp[base + c16] = lg0;
    outp[base + 16 + c16] = lg1;
    int targ = targ_s[t];
    if (targ != 0 && c16 == (targ & 15)) {
      float lt = (targ >> 4) ? lg1 : lg0;
      nll_acc += lse - lt; cnt_acc += 1.f;
    }
  }

#pragma unroll
  for (int off = 32; off >= 1; off >>= 1) {
    nll_acc += __shfl_xor(nll_acc, off);
    cnt_acc += __shfl_xor(cnt_acc, off);
  }
  if (lane == 0) { red_s[w] = nll_acc; red_s[4 + w] = cnt_acc; }
  __syncthreads();
  if (tid == 0) {
    atomicAdd(&ws[0], red_s[0] + red_s[1] + red_s[2] + red_s[3]);
    atomicAdd(&ws[1], red_s[4] + red_s[5] + red_s[6] + red_s[7]);
  }
}

__global__ void loss_kernel(const float* __restrict__ ws, float* __restrict__ outp) {
  if (threadIdx.x == 0)
    outp[(size_t)Bsz * Tn * Vn] = ws[0] / fmaxf(ws[1], 1.f);
}

extern "C" void kernel_launch(void* const* d_in, const int* in_sizes, int n_in,
                              void* d_out, int out_size, void* d_ws, size_t ws_size,
                              hipStream_t stream) {
  const float* phon = (const float*)d_in[0];
  const int*   cs   = (const int*)d_in[1];
  const float* emb  = (const float*)d_in[2];
  const float* Wrx  = (const float*)d_in[3];
  const float* brx  = (const float*)d_in[4];
  const float* Wrh  = (const float*)d_in[5];
  const float* brh  = (const float*)d_in[6];
  const float* Wzx  = (const float*)d_in[7];
  const float* bzx  = (const float*)d_in[8];
  const float* Wzh  = (const float*)d_in[9];
  const float* bzh  = (const float*)d_in[10];
  const float* Whx  = (const float*)d_in[11];
  const float* bhx  = (const float*)d_in[12];
  const float* Whh  = (const float*)d_in[13];
  const float* bhh  = (const float*)d_in[14];
  const float* Wpj  = (const float*)d_in[15];
  const float* bpj  = (const float*)d_in[16];
  float* ws = (float*)d_ws;

  hipLaunchKernelGGL(zero_kernel, dim3(1), dim3(64), 0, stream, ws);
  hipLaunchKernelGGL(gru_scan, dim3(Bsz / 16), dim3(256), 0, stream,
                     phon, cs, emb, Wrx, brx, Wrh, brh, Wzx, bzx, Wzh, bzh,
                     Whx, bhx, Whh, bhh, (unsigned short*)d_out);
  hipLaunchKernelGGL(proj_kernel, dim3(Bsz), dim3(256), 0, stream,
                     cs, Wpj, bpj, ws, (float*)d_out);
  hipLaunchKernelGGL(loss_kernel, dim3(1), dim3(64), 0, stream, ws, (float*)d_out);
}